// Round 1
// baseline (156.050 us; speedup 1.0000x reference)
//
#include <hip/hip_runtime.h>
#include <hip/hip_bf16.h>
#include <stdint.h>

using bf16 = __hip_bfloat16;
typedef __attribute__((ext_vector_type(8))) short bf16x8;
typedef __attribute__((ext_vector_type(4))) float f32x4;

// ---------------------------------------------------------------------------
// async global->LDS, 16B per lane, wave-uniform LDS base (guide §5, m97/m173)
// ---------------------------------------------------------------------------
__device__ __forceinline__ void gload_lds16(const void* g, void* l) {
  __builtin_amdgcn_global_load_lds(
      (__attribute__((address_space(1))) void*)(g),
      (__attribute__((address_space(3))) void*)(l), 16, 0, 0);
}

__device__ __forceinline__ unsigned short bf16_bits(float f) {
  bf16 b = __float2bfloat16(f);
  return *reinterpret_cast<unsigned short*>(&b);
}

// ---------------------------------------------------------------------------
// f32 -> bf16 conversion, vectorized (float4 in, ushort4 out)
// ---------------------------------------------------------------------------
__global__ __launch_bounds__(256) void cvt_f32_bf16(
    const float* __restrict__ in, unsigned short* __restrict__ out, int n4) {
  int i = blockIdx.x * 256 + threadIdx.x;
  if (i >= n4) return;
  float4 f = reinterpret_cast<const float4*>(in)[i];
  ushort4 u;
  u.x = bf16_bits(f.x);
  u.y = bf16_bits(f.y);
  u.z = bf16_bits(f.z);
  u.w = bf16_bits(f.w);
  reinterpret_cast<ushort4*>(out)[i] = u;
}

// ---------------------------------------------------------------------------
// NT GEMM: C[m][n] = scale * sum_k A[m][k] * B[n][k]  (+ bias)
//   A: [M][K] row-major, B: [N][K] row-major, C: [M][N] row-major
//   128x128 tile, BK=64, 4 waves (2x2 of 64x64), mfma 16x16x32 bf16
//   LDS tiles XOR-swizzled via pre-swizzled global source (T2 / m173)
//   split-K via blockIdx.z: each z writes its own C partial (Cout + z*M*N)
// BIAS_MODE: 0 none, 1 bias[row], 2 bias[col].  OUT_BF16: 1 -> bf16 C.
// ---------------------------------------------------------------------------
template <int BIAS_MODE, int OUT_BF16>
__global__ __launch_bounds__(256, 2) void gemm_nt(
    const bf16* __restrict__ A, const bf16* __restrict__ B,
    const float* __restrict__ bias, void* __restrict__ Cout, int M, int N,
    int K, int kChunk, float scale) {
  __shared__ __align__(128) char lds[32768];  // A tile 16KB @0, B tile @16384
  const int tid = threadIdx.x;
  const int lane = tid & 63;
  const int wv = tid >> 6;
  const int wm = wv >> 1, wn = wv & 1;
  const int m0 = blockIdx.y * 128, n0 = blockIdx.x * 128;
  const int kBegin = blockIdx.z * kChunk;

  // staging: per wave 4 instrs x 1KB per tile; LDS linear, global pre-swizzled
  const char* srcA[4];
  const char* srcB[4];
  char* dstA[4];
  char* dstB[4];
#pragma unroll
  for (int t = 0; t < 4; ++t) {
    int o = wv * 4096 + t * 1024 + lane * 16;  // linear LDS byte offset
    int row = o >> 7;                          // tile row (128B per row)
    int gcb = (o & 127) ^ ((row & 7) << 4);    // inverse-swizzled global col
    srcA[t] = (const char*)A + ((size_t)(m0 + row) * K + kBegin) * 2 + gcb;
    srcB[t] = (const char*)B + ((size_t)(n0 + row) * K + kBegin) * 2 + gcb;
    dstA[t] = lds + wv * 4096 + t * 1024;
    dstB[t] = lds + 16384 + wv * 4096 + t * 1024;
  }

  // per-lane ds_read offsets (swizzled)
  const int xorv = (lane & 7) << 4;
  const int rowOff = (lane & 15) * 128;
  const int colHi = (lane >> 4) << 4;  // k sub-offset: {0,16,32,48} bytes

  f32x4 acc[4][4] = {};
  const int nk = kChunk >> 6;
  for (int kt = 0; kt < nk; ++kt) {
#pragma unroll
    for (int t = 0; t < 4; ++t) gload_lds16(srcA[t], dstA[t]);
#pragma unroll
    for (int t = 0; t < 4; ++t) gload_lds16(srcB[t], dstB[t]);
#pragma unroll
    for (int t = 0; t < 4; ++t) {
      srcA[t] += 128;  // advance 64 bf16 in k
      srcB[t] += 128;
    }
    __syncthreads();  // drains vmcnt -> tile visible to all waves
#pragma unroll
    for (int h = 0; h < 2; ++h) {
      const int kk64 = h * 64;
      bf16x8 af[4], bfr[4];
#pragma unroll
      for (int f = 0; f < 4; ++f) {
        int offA = ((wm * 64 + f * 16) * 128) + rowOff + ((kk64 + colHi) ^ xorv);
        af[f] = *reinterpret_cast<const bf16x8*>(lds + offA);
      }
#pragma unroll
      for (int f = 0; f < 4; ++f) {
        int offB =
            16384 + ((wn * 64 + f * 16) * 128) + rowOff + ((kk64 + colHi) ^ xorv);
        bfr[f] = *reinterpret_cast<const bf16x8*>(lds + offB);
      }
#pragma unroll
      for (int m = 0; m < 4; ++m)
#pragma unroll
        for (int n = 0; n < 4; ++n)
          acc[m][n] = __builtin_amdgcn_mfma_f32_16x16x32_bf16(af[m], bfr[n],
                                                              acc[m][n], 0, 0, 0);
    }
    __syncthreads();  // all waves done reading before next stage
  }

  // epilogue: C/D layout col=lane&15, row=(lane>>4)*4+r (guide §3, m89)
  char* Cbase = (char*)Cout + (size_t)blockIdx.z * M * N * (OUT_BF16 ? 2 : 4);
#pragma unroll
  for (int m = 0; m < 4; ++m) {
    const int grow = m0 + wm * 64 + m * 16 + ((lane >> 4) << 2);
#pragma unroll
    for (int n = 0; n < 4; ++n) {
      const int gcol = n0 + wn * 64 + n * 16 + (lane & 15);
#pragma unroll
      for (int r = 0; r < 4; ++r) {
        float v = acc[m][n][r] * scale;
        if (BIAS_MODE == 1) v += bias[grow + r];
        if (BIAS_MODE == 2) v += bias[gcol];
        if (OUT_BF16)
          ((bf16*)Cbase)[(size_t)(grow + r) * N + gcol] = __float2bfloat16(v);
        else
          ((float*)Cbase)[(size_t)(grow + r) * N + gcol] = v;
      }
    }
  }
}

// ---------------------------------------------------------------------------
// row-softmax of St (= column-softmax of S), summing 4 split-K partials.
// St: [4][1024][1024] f32 partials; At: [1024][1024] bf16 (= atten^T)
// one block per row j
// ---------------------------------------------------------------------------
__global__ __launch_bounds__(256) void softmax_rows(
    const float* __restrict__ Sp, bf16* __restrict__ At) {
  const int j = blockIdx.x;
  const int tid = threadIdx.x;
  const int lane = tid & 63, wv = tid >> 6;
  float v[4];
#pragma unroll
  for (int t = 0; t < 4; ++t) {
    const int i = tid + 256 * t;
    float s = 0.f;
#pragma unroll
    for (int sp = 0; sp < 4; ++sp)
      s += Sp[((size_t)sp << 20) + (size_t)j * 1024 + i];
    v[t] = s;
  }
  float m = fmaxf(fmaxf(v[0], v[1]), fmaxf(v[2], v[3]));
#pragma unroll
  for (int off = 32; off; off >>= 1) m = fmaxf(m, __shfl_xor(m, off));
  __shared__ float red[8];
  if (lane == 0) red[wv] = m;
  __syncthreads();
  m = fmaxf(fmaxf(red[0], red[1]), fmaxf(red[2], red[3]));
  float p[4], s = 0.f;
#pragma unroll
  for (int t = 0; t < 4; ++t) {
    p[t] = __expf(v[t] - m);
    s += p[t];
  }
#pragma unroll
  for (int off = 32; off; off >>= 1) s += __shfl_xor(s, off);
  if (lane == 0) red[4 + wv] = s;
  __syncthreads();
  const float inv = 1.f / (red[4] + red[5] + red[6] + red[7]);
#pragma unroll
  for (int t = 0; t < 4; ++t)
    At[(size_t)j * 1024 + tid + 256 * t] = __float2bfloat16(p[t] * inv);
}

// ---------------------------------------------------------------------------
extern "C" void kernel_launch(void* const* d_in, const int* in_sizes, int n_in,
                              void* d_out, int out_size, void* d_ws,
                              size_t ws_size, hipStream_t stream) {
  const float* x = (const float*)d_in[0];
  const float* Wq = (const float*)d_in[1];
  const float* bq = (const float*)d_in[2];
  const float* Wk = (const float*)d_in[3];
  const float* bk = (const float*)d_in[4];
  const float* Wv = (const float*)d_in[5];
  const float* bv = (const float*)d_in[6];

  const int N = 8192, D = 1024;  // rows, feature dim (= dim_k = dim_v)
  char* ws = (char*)d_ws;
  const size_t MB = 1ull << 20;
  // region 0 (16MB) is xb, later reused as Sp (xb's last read is GEMM V,
  // which is launched before the Sp-producing GEMM on the same stream).
  bf16* xb = (bf16*)(ws);                  // [8192][1024] bf16, 16MB
  float* Sp = (float*)(ws);                // [4][1024][1024] f32, 16MB (alias)
  bf16* Wqb = (bf16*)(ws + 16 * MB);       // 2MB
  bf16* Wkb = (bf16*)(ws + 18 * MB);       // 2MB
  bf16* Wvb = (bf16*)(ws + 20 * MB);       // 2MB
  bf16* Qt = (bf16*)(ws + 22 * MB);        // [1024][8192] bf16, 16MB
  bf16* Kt = (bf16*)(ws + 38 * MB);        // [1024][8192] bf16, 16MB
  bf16* V = (bf16*)(ws + 54 * MB);         // [8192][1024] bf16, 16MB
  bf16* At = (bf16*)(ws + 70 * MB);        // [1024][1024] bf16, 2MB
  (void)ws_size;
  (void)in_sizes;
  (void)n_in;
  (void)out_size;

  const float norm = 0.03125f;  // 1/sqrt(1024)

  // f32 -> bf16
  cvt_f32_bf16<<<(N * D / 4 + 255) / 256, 256, 0, stream>>>(x, (unsigned short*)xb,
                                                            N * D / 4);
  cvt_f32_bf16<<<(D * D / 4 + 255) / 256, 256, 0, stream>>>(Wq, (unsigned short*)Wqb,
                                                            D * D / 4);
  cvt_f32_bf16<<<(D * D / 4 + 255) / 256, 256, 0, stream>>>(Wk, (unsigned short*)Wkb,
                                                            D * D / 4);
  cvt_f32_bf16<<<(D * D / 4 + 255) / 256, 256, 0, stream>>>(Wv, (unsigned short*)Wvb,
                                                            D * D / 4);

  // Qt[i][n] = sum_k Wq[i][k] * x[n][k] + bq[i]   -> [1024][8192] bf16
  gemm_nt<1, 1><<<dim3(N / 128, D / 128), 256, 0, stream>>>(Wqb, xb, bq, Qt, D, N,
                                                            D, D, 1.0f);
  // Kt[i][n] likewise
  gemm_nt<1, 1><<<dim3(N / 128, D / 128), 256, 0, stream>>>(Wkb, xb, bk, Kt, D, N,
                                                            D, D, 1.0f);
  // V[n][j] = sum_k x[n][k] * Wv[j][k] + bv[j]    -> [8192][1024] bf16
  gemm_nt<2, 1><<<dim3(D / 128, N / 128), 256, 0, stream>>>(xb, Wvb, bv, V, N, D,
                                                            D, D, 1.0f);
  // St[j][i] = norm * sum_n Kt[j][n] * Qt[i][n], split-K=4 partials (f32)
  gemm_nt<0, 0><<<dim3(D / 128, D / 128, 4), 256, 0, stream>>>(
      Kt, Qt, nullptr, Sp, D, D, N, N / 4, norm);
  // atten^T = row-softmax(sum of partials)        -> [1024][1024] bf16
  softmax_rows<<<D, 256, 0, stream>>>(Sp, At);
  // out[n][j] = sum_k V[n][k] * At[j][k]          -> [8192][1024] f32
  gemm_nt<0, 0><<<dim3(D / 128, N / 128), 256, 0, stream>>>(V, At, nullptr, d_out,
                                                            N, D, D, D, 1.0f);
}

// Round 2
// 147.754 us; speedup vs baseline: 1.0561x; 1.0561x over previous
//
#include <hip/hip_runtime.h>
#include <hip/hip_bf16.h>
#include <stdint.h>

using bf16 = __hip_bfloat16;
typedef __attribute__((ext_vector_type(8))) short bf16x8;
typedef __attribute__((ext_vector_type(4))) float f32x4;

// ---------------------------------------------------------------------------
// async global->LDS, 16B per lane, wave-uniform LDS base (guide §5, m97/m173)
// ---------------------------------------------------------------------------
__device__ __forceinline__ void gload_lds16(const void* g, void* l) {
  __builtin_amdgcn_global_load_lds(
      (__attribute__((address_space(1))) void*)(g),
      (__attribute__((address_space(3))) void*)(l), 16, 0, 0);
}

__device__ __forceinline__ unsigned short bf16_bits(float f) {
  bf16 b = __float2bfloat16(f);
  return *reinterpret_cast<unsigned short*>(&b);
}

// ---------------------------------------------------------------------------
// f32 -> bf16 conversion, vectorized (float4 in, ushort4 out)
// ---------------------------------------------------------------------------
__global__ __launch_bounds__(256) void cvt_f32_bf16(
    const float* __restrict__ in, unsigned short* __restrict__ out, int n4) {
  int i = blockIdx.x * 256 + threadIdx.x;
  if (i >= n4) return;
  float4 f = reinterpret_cast<const float4*>(in)[i];
  ushort4 u;
  u.x = bf16_bits(f.x);
  u.y = bf16_bits(f.y);
  u.z = bf16_bits(f.z);
  u.w = bf16_bits(f.w);
  reinterpret_cast<ushort4*>(out)[i] = u;
}

// pack two 1024-float bias vectors into one contiguous 2048-float buffer
__global__ __launch_bounds__(256) void pack_bias(const float* __restrict__ a,
                                                 const float* __restrict__ b,
                                                 float* __restrict__ out) {
  int i = blockIdx.x * 256 + threadIdx.x;
  out[i] = (i < 1024) ? a[i] : b[i - 1024];
}

// ---------------------------------------------------------------------------
// NT GEMM: C[m][n] = scale * sum_k A[m][k] * B[n][k]  (+ bias)
//   A: [M][K] row-major, B: [N][K] row-major, C: [M][N] row-major
//   128x128 tile, BK=64, 4 waves (2x2 of 64x64), mfma 16x16x32 bf16
//   LDS tiles XOR-swizzled via pre-swizzled global source (T2 / m173)
//   split-K via blockIdx.z: each z writes its own C partial (Cout + z*M*N)
// BIAS_MODE: 0 none, 1 bias[row], 2 bias[col].  OUT_BF16: 1 -> bf16 C.
// SWAP: 1 -> blockIdx.x maps to M-tiles (fast axis = small A, shares B panel)
// XCD_SWZ: 1 -> T1 chunked swizzle (requires gridDim.x*gridDim.y % 8 == 0)
// ---------------------------------------------------------------------------
template <int BIAS_MODE, int OUT_BF16, int SWAP, int XCD_SWZ>
__global__ __launch_bounds__(256, 2) void gemm_nt(
    const bf16* __restrict__ A, const bf16* __restrict__ B,
    const float* __restrict__ bias, void* __restrict__ Cout, int M, int N,
    int K, int kChunk, float scale) {
  __shared__ __align__(128) char lds[32768];  // A tile 16KB @0, B tile @16384
  const int tid = threadIdx.x;
  const int lane = tid & 63;
  const int wv = tid >> 6;
  const int wm = wv >> 1, wn = wv & 1;

  int mt, nt;
  if (XCD_SWZ) {
    int lin = blockIdx.y * gridDim.x + blockIdx.x;  // dispatch order (x fast)
    int cpx = (gridDim.x * gridDim.y) >> 3;         // nwg % 8 == 0 required
    int swz = (lin & 7) * cpx + (lin >> 3);
    if (SWAP) {
      mt = swz % gridDim.x;
      nt = swz / gridDim.x;
    } else {
      nt = swz % gridDim.x;
      mt = swz / gridDim.x;
    }
  } else {
    if (SWAP) {
      mt = blockIdx.x;
      nt = blockIdx.y;
    } else {
      nt = blockIdx.x;
      mt = blockIdx.y;
    }
  }
  const int m0 = mt * 128, n0 = nt * 128;
  const int kBegin = blockIdx.z * kChunk;

  // staging: per wave 4 instrs x 1KB per tile; LDS linear, global pre-swizzled
  const char* srcA[4];
  const char* srcB[4];
  char* dstA[4];
  char* dstB[4];
#pragma unroll
  for (int t = 0; t < 4; ++t) {
    int o = wv * 4096 + t * 1024 + lane * 16;  // linear LDS byte offset
    int row = o >> 7;                          // tile row (128B per row)
    int gcb = (o & 127) ^ ((row & 7) << 4);    // inverse-swizzled global col
    srcA[t] = (const char*)A + ((size_t)(m0 + row) * K + kBegin) * 2 + gcb;
    srcB[t] = (const char*)B + ((size_t)(n0 + row) * K + kBegin) * 2 + gcb;
    dstA[t] = lds + wv * 4096 + t * 1024;
    dstB[t] = lds + 16384 + wv * 4096 + t * 1024;
  }

  // per-lane ds_read offsets (swizzled)
  const int xorv = (lane & 7) << 4;
  const int rowOff = (lane & 15) * 128;
  const int colHi = (lane >> 4) << 4;  // k sub-offset: {0,16,32,48} bytes

  f32x4 acc[4][4] = {};
  const int nk = kChunk >> 6;
  for (int kt = 0; kt < nk; ++kt) {
#pragma unroll
    for (int t = 0; t < 4; ++t) gload_lds16(srcA[t], dstA[t]);
#pragma unroll
    for (int t = 0; t < 4; ++t) gload_lds16(srcB[t], dstB[t]);
#pragma unroll
    for (int t = 0; t < 4; ++t) {
      srcA[t] += 128;  // advance 64 bf16 in k
      srcB[t] += 128;
    }
    __syncthreads();  // drains vmcnt -> tile visible to all waves
#pragma unroll
    for (int h = 0; h < 2; ++h) {
      const int kk64 = h * 64;
      bf16x8 af[4], bfr[4];
#pragma unroll
      for (int f = 0; f < 4; ++f) {
        int offA = ((wm * 64 + f * 16) * 128) + rowOff + ((kk64 + colHi) ^ xorv);
        af[f] = *reinterpret_cast<const bf16x8*>(lds + offA);
      }
#pragma unroll
      for (int f = 0; f < 4; ++f) {
        int offB =
            16384 + ((wn * 64 + f * 16) * 128) + rowOff + ((kk64 + colHi) ^ xorv);
        bfr[f] = *reinterpret_cast<const bf16x8*>(lds + offB);
      }
#pragma unroll
      for (int m = 0; m < 4; ++m)
#pragma unroll
        for (int n = 0; n < 4; ++n)
          acc[m][n] = __builtin_amdgcn_mfma_f32_16x16x32_bf16(af[m], bfr[n],
                                                              acc[m][n], 0, 0, 0);
    }
    __syncthreads();  // all waves done reading before next stage
  }

  // epilogue: C/D layout col=lane&15, row=(lane>>4)*4+r (guide §3, m89)
  char* Cbase = (char*)Cout + (size_t)blockIdx.z * M * N * (OUT_BF16 ? 2 : 4);
#pragma unroll
  for (int m = 0; m < 4; ++m) {
    const int grow = m0 + wm * 64 + m * 16 + ((lane >> 4) << 2);
#pragma unroll
    for (int n = 0; n < 4; ++n) {
      const int gcol = n0 + wn * 64 + n * 16 + (lane & 15);
#pragma unroll
      for (int r = 0; r < 4; ++r) {
        float v = acc[m][n][r] * scale;
        if (BIAS_MODE == 1) v += bias[grow + r];
        if (BIAS_MODE == 2) v += bias[gcol];
        if (OUT_BF16)
          ((bf16*)Cbase)[(size_t)(grow + r) * N + gcol] = __float2bfloat16(v);
        else
          ((float*)Cbase)[(size_t)(grow + r) * N + gcol] = v;
      }
    }
  }
}

// ---------------------------------------------------------------------------
// row-softmax of St (= column-softmax of S), summing 4 split-K partials.
// Sp: [4][1024][1024] f32 partials; At: [1024][1024] bf16 (= atten^T)
// one block per row j
// ---------------------------------------------------------------------------
__global__ __launch_bounds__(256) void softmax_rows(
    const float* __restrict__ Sp, bf16* __restrict__ At) {
  const int j = blockIdx.x;
  const int tid = threadIdx.x;
  const int lane = tid & 63, wv = tid >> 6;
  float v[4];
#pragma unroll
  for (int t = 0; t < 4; ++t) {
    const int i = tid + 256 * t;
    float s = 0.f;
#pragma unroll
    for (int sp = 0; sp < 4; ++sp)
      s += Sp[((size_t)sp << 20) + (size_t)j * 1024 + i];
    v[t] = s;
  }
  float m = fmaxf(fmaxf(v[0], v[1]), fmaxf(v[2], v[3]));
#pragma unroll
  for (int off = 32; off; off >>= 1) m = fmaxf(m, __shfl_xor(m, off));
  __shared__ float red[8];
  if (lane == 0) red[wv] = m;
  __syncthreads();
  m = fmaxf(fmaxf(red[0], red[1]), fmaxf(red[2], red[3]));
  float p[4], s = 0.f;
#pragma unroll
  for (int t = 0; t < 4; ++t) {
    p[t] = __expf(v[t] - m);
    s += p[t];
  }
#pragma unroll
  for (int off = 32; off; off >>= 1) s += __shfl_xor(s, off);
  if (lane == 0) red[4 + wv] = s;
  __syncthreads();
  const float inv = 1.f / (red[4] + red[5] + red[6] + red[7]);
#pragma unroll
  for (int t = 0; t < 4; ++t)
    At[(size_t)j * 1024 + tid + 256 * t] = __float2bfloat16(p[t] * inv);
}

// ---------------------------------------------------------------------------
extern "C" void kernel_launch(void* const* d_in, const int* in_sizes, int n_in,
                              void* d_out, int out_size, void* d_ws,
                              size_t ws_size, hipStream_t stream) {
  const float* x = (const float*)d_in[0];
  const float* Wq = (const float*)d_in[1];
  const float* bq = (const float*)d_in[2];
  const float* Wk = (const float*)d_in[3];
  const float* bk = (const float*)d_in[4];
  const float* Wv = (const float*)d_in[5];
  const float* bv = (const float*)d_in[6];

  const int N = 8192, D = 1024;  // rows, feature dim (= dim_k = dim_v)
  char* ws = (char*)d_ws;
  const size_t MB = 1ull << 20;
  // region 0 (16MB) is xb, later reused as Sp (xb's last read is GEMM V,
  // which is launched before the Sp-producing GEMM on the same stream).
  bf16* xb = (bf16*)(ws);              // [8192][1024] bf16, 16MB
  float* Sp = (float*)(ws);            // [4][1024][1024] f32, 16MB (alias)
  bf16* Wqkb = (bf16*)(ws + 16 * MB);  // [2048][1024] bf16 (Wq || Wk), 4MB
  bf16* Wvb = (bf16*)(ws + 20 * MB);   // 2MB
  bf16* QtKt = (bf16*)(ws + 22 * MB);  // [2048][8192] bf16 (Qt || Kt), 32MB
  bf16* Qt = QtKt;                     // [1024][8192]
  bf16* Kt = (bf16*)(ws + 38 * MB);    // [1024][8192]
  bf16* V = (bf16*)(ws + 54 * MB);     // [8192][1024] bf16, 16MB
  bf16* At = (bf16*)(ws + 70 * MB);    // [1024][1024] bf16, 2MB
  float* bqk = (float*)(ws + 72 * MB);  // [2048] f32 packed bias, 8KB
  (void)ws_size;
  (void)in_sizes;
  (void)n_in;
  (void)out_size;

  const float norm = 0.03125f;  // 1/sqrt(1024)

  // f32 -> bf16
  cvt_f32_bf16<<<(N * D / 4 + 255) / 256, 256, 0, stream>>>(
      x, (unsigned short*)xb, N * D / 4);
  cvt_f32_bf16<<<(D * D / 4 + 255) / 256, 256, 0, stream>>>(
      Wq, (unsigned short*)Wqkb, D * D / 4);
  cvt_f32_bf16<<<(D * D / 4 + 255) / 256, 256, 0, stream>>>(
      Wk, (unsigned short*)(Wqkb + (size_t)D * D), D * D / 4);
  cvt_f32_bf16<<<(D * D / 4 + 255) / 256, 256, 0, stream>>>(
      Wv, (unsigned short*)Wvb, D * D / 4);
  pack_bias<<<8, 256, 0, stream>>>(bq, bk, bqk);

  // [Qt;Kt][i][n] = sum_k Wqk[i][k] * x[n][k] + bqk[i]  -> [2048][8192] bf16
  // SWAP=1: x-axis walks M-tiles (share xb n-panel); XCD_SWZ=1 (1024 blocks)
  gemm_nt<1, 1, 1, 1><<<dim3(2 * D / 128, N / 128), 256, 0, stream>>>(
      Wqkb, xb, bqk, QtKt, 2 * D, N, D, D, 1.0f);
  // V[n][j] = sum_k x[n][k] * Wv[j][k] + bv[j]    -> [8192][1024] bf16
  // (x fast over 8 Wv panels = 2MB, L2-resident: already the good mapping)
  gemm_nt<2, 1, 0, 0><<<dim3(D / 128, N / 128), 256, 0, stream>>>(
      xb, Wvb, bv, V, N, D, D, D, 1.0f);
  // St[j][i] = norm * sum_n Kt[j][n] * Qt[i][n], split-K=4 partials (f32)
  gemm_nt<0, 0, 0, 0><<<dim3(D / 128, D / 128, 4), 256, 0, stream>>>(
      Kt, Qt, nullptr, Sp, D, D, N, N / 4, norm);
  // atten^T = row-softmax(sum of partials)        -> [1024][1024] bf16
  softmax_rows<<<D, 256, 0, stream>>>(Sp, At);
  // out[n][j] = sum_k V[n][k] * At[j][k]          -> [8192][1024] f32
  gemm_nt<0, 0, 0, 0><<<dim3(D / 128, N / 128), 256, 0, stream>>>(
      V, At, nullptr, d_out, N, D, D, D, 1.0f);
}